// Round 2
// baseline (252.574 us; speedup 1.0000x reference)
//
#include <hip/hip_runtime.h>
#include <hip/hip_bf16.h>
#include <cmath>

#define NB 4
#define NM 32
#define DKc 256
#define DVc 32
#define NP 4096

using bf16x8 = __attribute__((ext_vector_type(8))) short;
using f32x4  = __attribute__((ext_vector_type(4))) float;
using f32x2  = __attribute__((ext_vector_type(2))) float;

__device__ __forceinline__ unsigned short f2bf(float f) {
    union { float f; unsigned u; } x; x.f = f;
    unsigned r = 0x7FFFu + ((x.u >> 16) & 1u);
    return (unsigned short)((x.u + r) >> 16);
}

// ---------------- k_prep: fc transpose (1024 blocks) + W transposes (32) + vproj (64) ----------------
__global__ __launch_bounds__(256) void k_prep(
    const float* __restrict__ fc, unsigned short* __restrict__ fcT,
    const float* __restrict__ Q, unsigned short* __restrict__ WTq,
    const float* __restrict__ K, unsigned short* __restrict__ WTk,
    const float* __restrict__ fm, const float* __restrict__ V, float* __restrict__ vproj) {
    int x = blockIdx.x;
    int t = threadIdx.x;
    if (x < 1056) {
        __shared__ float tile[64][65];
        const float* s; unsigned short* d; int R, C, r0, c0;
        if (x < 1024) {
            int bb = x >> 8, rest = x & 255;
            R = 256; C = 4096;
            r0 = (rest >> 6) * 64; c0 = (rest & 63) * 64;
            s = fc + (long)bb * 256 * 4096; d = fcT + (long)bb * 256 * 4096;
        } else {
            int i = x - 1024;
            int mat = i >> 4, idx = i & 15;
            R = 256; C = 256;
            r0 = (idx >> 2) * 64; c0 = (idx & 3) * 64;
            s = mat ? K : Q; d = mat ? WTk : WTq;
        }
        #pragma unroll
        for (int j = 0; j < 16; ++j) {
            int i = t + 256 * j;
            int r = i >> 6, c = i & 63;
            tile[r][c] = s[(long)(r0 + r) * C + c0 + c];
        }
        __syncthreads();
        #pragma unroll
        for (int j = 0; j < 8; ++j) {
            int i = t + 256 * j;
            int row = i >> 5;
            int pr = i & 31;
            float f0 = tile[2 * pr][row];
            float f1 = tile[2 * pr + 1][row];
            unsigned pack = (unsigned)f2bf(f0) | ((unsigned)f2bf(f1) << 16);
            reinterpret_cast<unsigned*>(d)[(((long)(c0 + row) * R + r0) >> 1) + pr] = pack;
        }
    } else {
        __shared__ float Vl[32][32];
        __shared__ float fml[32][256];
        int i = x - 1056;
        int b = i >> 4, p0 = (i & 15) * 256;
        #pragma unroll
        for (int j = 0; j < 4; ++j) { int ii = t + 256 * j; Vl[ii >> 5][ii & 31] = V[ii]; }
        for (int j = 0; j < 32; ++j) {
            int ii = t + 256 * j;
            int dd = ii >> 8, c = ii & 255;
            fml[dd][c] = fm[((long)b * DVc + dd) * NP + p0 + c];
        }
        __syncthreads();
        float acc[32];
        #pragma unroll
        for (int e = 0; e < 32; ++e) acc[e] = 0.f;
        for (int dd = 0; dd < 32; ++dd) {
            float fv = fml[dd][t];
            #pragma unroll
            for (int e = 0; e < 32; ++e) acc[e] += fv * Vl[dd][e];
        }
        #pragma unroll
        for (int e = 0; e < 32; ++e) vproj[((long)b * DVc + e) * NP + p0 + t] = acc[e];
    }
}

// ---------------- k_proj: full-e (256) per 64-p tile. grid (64, 8=b*mat) ----------------
// both outputs fp32 [b][e][p]: mat==0 -> qproj, mat==1 -> kproj
__global__ __launch_bounds__(256) void k_proj(
    const unsigned short* __restrict__ WTq, const unsigned short* __restrict__ WTk,
    const unsigned short* __restrict__ fcT,
    float* __restrict__ qproj, float* __restrict__ kproj) {
    int t = threadIdx.x;
    int wave = t >> 6, lane = t & 63;
    int y = blockIdx.y;
    int b = y & 3, mat = y >> 2;
    int p0 = blockIdx.x * 64;
    int ln = lane & 15, quad = lane >> 4;
    const unsigned short* WT = mat ? WTk : WTq;
    float* dst = mat ? kproj : qproj;
    int e0w = wave * 64;
    const unsigned short* bbase = fcT + ((long)b * NP + p0 + ln) * DKc + quad * 8;
    f32x4 acc[4][4] = {};
    for (int kk = 0; kk < DKc; kk += 32) {
        bf16x8 a[4], bb[4];
        #pragma unroll
        for (int i = 0; i < 4; ++i)
            a[i] = *reinterpret_cast<const bf16x8*>(WT + (long)(e0w + i * 16 + ln) * DKc + quad * 8 + kk);
        #pragma unroll
        for (int j = 0; j < 4; ++j)
            bb[j] = *reinterpret_cast<const bf16x8*>(bbase + (long)j * 16 * DKc + kk);
        #pragma unroll
        for (int i = 0; i < 4; ++i)
            #pragma unroll
            for (int j = 0; j < 4; ++j)
                acc[i][j] = __builtin_amdgcn_mfma_f32_16x16x32_bf16(a[i], bb[j], acc[i][j], 0, 0, 0);
    }
    #pragma unroll
    for (int i = 0; i < 4; ++i)
        #pragma unroll
        for (int j = 0; j < 4; ++j)
            #pragma unroll
            for (int r = 0; r < 4; ++r) {
                int e = e0w + i * 16 + quad * 4 + r, p = p0 + j * 16 + ln;
                dst[((long)b * DKc + e) * NP + p] = acc[i][j][r];
            }
}

// ---------------- k_fused: scores + softmax(w) + ctx + epilogue, one pass ----------------
// grid 256 (b*64+hrow), 1024 thr (16 waves, 4 waves/SIMD).
// LDS: single 64 KiB buffer. Phase 1-2 use it as qs[256][64] (q tile);
// after a consume-barrier it is reused as sc[32][68] (attn weights).
// Static LDS = 65536 B exactly (the 64 KiB per-WG limit; 74 KB failed to launch).
// The 4 b-siblings (blockIdx 64 apart => same XCD) issue the identical k/v
// address stream => per-XCD L2 serves the 4x read amplification.
__global__ __launch_bounds__(1024) void k_fused(
    const float* __restrict__ qproj, const float* __restrict__ kproj,
    const float* __restrict__ kbuf, const float* __restrict__ vproj,
    const float* __restrict__ vbuf, const float* __restrict__ fm,
    float* __restrict__ out, float scale) {
    __shared__ float smem[256 * 64];           // 65536 B: qs then sc (aliased)
    int t = threadIdx.x;
    int b = blockIdx.x >> 6, hrow = blockIdx.x & 63;
    int p0 = hrow * 64;
    int wave = t >> 6, lane = t & 63;

    // phase 1: stage q[b][e][p0+w] -> qs[e][w]  (read exactly once; coalesced 256B rows)
    {
        const float* qbase = qproj + (long)b * DKc * NP + p0;
        #pragma unroll
        for (int j = 0; j < 16; ++j) {
            int i = t + 1024 * j;
            int e = i >> 6, w = i & 63;
            smem[e * 64 + w] = qbase[(long)e * NP + w];
        }
    }
    __syncthreads();

    // phase 2: scores. Each wave owns 2 m-rows; lane = w.
    float attnw[2];
    {
        const float* kp[2];
        #pragma unroll
        for (int mi = 0; mi < 2; ++mi) {
            int m = wave * 2 + mi;
            kp[mi] = (m < 4 ? kproj + (long)m * DKc * NP : kbuf + (long)(m - 4) * DKc * NP)
                     + p0 + lane;
        }
        float s[2] = {0.f, 0.f};
        for (int e8 = 0; e8 < 256; e8 += 8) {
            float qv[8], kv[8][2];
            #pragma unroll
            for (int u = 0; u < 8; ++u) qv[u] = smem[(e8 + u) * 64 + lane];
            #pragma unroll
            for (int u = 0; u < 8; ++u)
                #pragma unroll
                for (int mi = 0; mi < 2; ++mi)
                    kv[u][mi] = kp[mi][(long)u * NP];
            #pragma unroll
            for (int u = 0; u < 8; ++u)
                #pragma unroll
                for (int mi = 0; mi < 2; ++mi)
                    s[mi] += qv[u] * kv[u][mi];
            #pragma unroll
            for (int mi = 0; mi < 2; ++mi) kp[mi] += 8 * NP;
        }
        // softmax over w (the 64 lanes of this wave) per row — registers/shuffles only
        #pragma unroll
        for (int mi = 0; mi < 2; ++mi) {
            float x = s[mi] * scale;
            float mx = x;
            #pragma unroll
            for (int d = 1; d < 64; d <<= 1) mx = fmaxf(mx, __shfl_xor(mx, d));
            float ev = __expf(x - mx);
            float sum = ev;
            #pragma unroll
            for (int d = 1; d < 64; d <<= 1) sum += __shfl_xor(sum, d);
            attnw[mi] = ev / sum;
        }
    }
    __syncthreads();   // all waves done READING qs -> safe to overwrite with sc
    #pragma unroll
    for (int mi = 0; mi < 2; ++mi)
        smem[(wave * 2 + mi) * 68 + lane] = attnw[mi];
    __syncthreads();

    // phase 3: ctx + epilogue. dg = t>>6 in [0,16), 2 d per group; w = lane.
    {
        int dg = t >> 6, w = t & 63;
        float c2[2] = {0.f, 0.f};
        #pragma unroll
        for (int m = 0; m < NM; ++m) {
            float a = smem[m * 68 + w];
            const float* vp = (m < 4 ? vproj + (long)m * DVc * NP : vbuf + (long)(m - 4) * DVc * NP)
                              + (long)(dg * 2) * NP + p0 + w;
            #pragma unroll
            for (int i = 0; i < 2; ++i) c2[i] += a * vp[(long)i * NP];
        }
        #pragma unroll
        for (int i = 0; i < 2; ++i) {
            long gi = ((long)b * DVc + dg * 2 + i) * NP + p0 + w;
            out[gi] = fm[gi] + 0.5f * c2[i];
        }
    }
}

extern "C" void kernel_launch(void* const* d_in, const int* in_sizes, int n_in,
                              void* d_out, int out_size, void* d_ws, size_t ws_size,
                              hipStream_t stream) {
    const float* fc = (const float*)d_in[0];
    const float* fm = (const float*)d_in[1];
    const float* kb = (const float*)d_in[2];
    const float* vb = (const float*)d_in[3];
    const float* Q  = (const float*)d_in[4];
    const float* K  = (const float*)d_in[5];
    const float* V  = (const float*)d_in[6];
    float* out = (float*)d_out;
    char* ws = (char*)d_ws;
    // layout: qproj/kproj/vproj persistent; fcT+WT dead after k_proj.
    float*          qproj = (float*)(ws);                          // 16777216 B
    float*          kproj = (float*)(ws + 16777216);               // 16777216 B
    float*          vproj = (float*)(ws + 33554432);               //  2097152 B
    unsigned short* fcT   = (unsigned short*)(ws + 35651584);      //  8388608 B
    unsigned short* WTq   = (unsigned short*)(ws + 44040192);      //   131072 B
    unsigned short* WTk   = (unsigned short*)(ws + 44171264);      //   131072 B
    float scale = (float)(log(135168.0) / log(1000.0) / 16.0);

    hipLaunchKernelGGL(k_prep, dim3(1120), dim3(256), 0, stream,
                       fc, fcT, Q, WTq, K, WTk, fm, V, vproj);
    hipLaunchKernelGGL(k_proj, dim3(64, 8), dim3(256), 0, stream,
                       WTq, WTk, fcT, qproj, kproj);
    hipLaunchKernelGGL(k_fused, dim3(256), dim3(1024), 0, stream,
                       qproj, kproj, kb, vproj, vb, fm, out, scale);
}